// Round 11
// baseline (235.140 us; speedup 1.0000x reference)
//
#include <hip/hip_runtime.h>

// AffinitySideLoss: B=4, E=12, H=W=512, S=8 offsets, output = 1 float scalar.
// d_in[0] = input_ float32 [4,12,512,512]
// d_in[1] = target int32   [4,1,512,512]
// d_in[2] = offsets int32  [8,2]  (values in [-27,0))
// d_out   = float32 [1]
// d_ws    = per-block partials: float [16][512]  (32 KB)
//
// R11: 32x64 supertile, double-buffered LDS halo (60x92 per channel),
// reg-staged (global->VGPR->ds_write; global_load_lds bypasses L3 - R6/R8),
// and RAW s_barrier + manual lgkmcnt wait instead of __syncthreads(): hipcc
// emits s_waitcnt vmcnt(0) before s_barrier for __syncthreads, which drains
// the cross-channel prefetch every iteration (the R9/R10 serialization).
// With the raw barrier, loads for channel e+2 issued at the bottom of iter
// e stay in flight across the barrier and compute(e+1); their vmcnt wait
// lands at stage_write one full phase later. Miss traffic: 512 blk x 13 ch
// x 22 KB = 147 MB (vs 490 MB direct-load) under the measured ~18.6
// B/cyc/CU L1-miss throughput cap.

typedef float f2 __attribute__((ext_vector_type(2)));
typedef float f4 __attribute__((ext_vector_type(4)));

#define HWSZ   262144     // 512*512
#define NE     12
#define NC     13         // 12 emb channels + seg channel
#define NS     8
#define TROWS  32
#define TCOLS  64
#define NBLK   512        // 4 batches x 16 row-tiles x 8 col-tiles
#define HROWS  60         // rows r0-28 .. r0+31
#define HCOLS  92         // cols c0-28 .. c0+63
#define NCHUNK 23         // f4 chunks per halo row (92/4)
#define NSLOT  1380       // HROWS*NCHUNK f4 slots; float idx = 4*slot

__global__ __launch_bounds__(512, 4) void affloss_main(
    const float* __restrict__ emb, const int* __restrict__ seg,
    const int* __restrict__ offs, float* __restrict__ partial) {
  __shared__ f4 buf4[2][NSLOT];         // 2 x 22,080 B
  __shared__ float red[8][16];

  // XCD swizzle (bijective, 512 % 8 == 0): contiguous tile band per XCD.
  const int bid = blockIdx.x;
  const int nb  = (bid & 7) * (NBLK / 8) + (bid >> 3);
  const int b   = nb >> 7;              // batch 0..3
  const int rem = nb & 127;             // 16 row-tiles x 8 col-tiles
  const int r0  = (rem >> 3) * TROWS;   // 0..480
  const int c0  = (rem & 7) * TCOLS;    // 0..448

  const int tid  = threadIdx.x;
  const int tx   = tid & 31;            // f2 col: tile cols 2tx, 2tx+1
  const int trow = tid >> 5;            // tile rows trow, trow+16
  const int wv   = tid >> 6;            // wave 0..7

  const float* embB = emb + (size_t)b * NE * HWSZ;
  const int*   segB = seg + (size_t)b * HWSZ;

  int soff[NS];                         // halo-space offset (uniform/scalar)
  #pragma unroll
  for (int s = 0; s < NS; ++s)
    soff[s] = offs[2 * s] * HCOLS + offs[2 * s + 1];

  // Staging geometry: f4 slot -> (halo row rr, chunk ch). Row clamps at 0
  // (replication, top only); fully-negative chunks (c0==0, cols<28) splat
  // col 0. Layout is linear: float index = 4*slot (92 = 4*23).
  int srow[3], sgc[3];
  #pragma unroll
  for (int k = 0; k < 3; ++k) {
    const int slot = tid + k * 512;
    const int rr = slot / NCHUNK;
    const int ch = slot - rr * NCHUNK;
    int gr = r0 - 28 + rr; gr = gr < 0 ? 0 : gr;
    srow[k] = gr << 9;
    sgc[k]  = c0 - 28 + 4 * ch;
  }
  const bool has2 = tid < (NSLOT - 1024);   // threads 0..355 own slot 3

  f4 r[3];
  auto stage_load = [&](int e) {            // issue global->reg loads
    const float* p = (e < NE) ? (embB + (size_t)e * HWSZ) : (const float*)segB;
    #pragma unroll
    for (int k = 0; k < 3; ++k) {
      if (k == 2 && !has2) continue;
      const float* rowp = p + srow[k];
      if (sgc[k] >= 0) {
        r[k] = *reinterpret_cast<const f4*>(rowp + sgc[k]);   // 16B aligned
      } else {
        const float v = rowp[0];                              // left-edge splat
        r[k] = f4{v, v, v, v};
      }
    }
  };
  auto stage_write = [&](int bi) {          // vmcnt wait lands here
    buf4[bi][tid] = r[0];
    buf4[bi][tid + 512] = r[1];
    if (has2) buf4[bi][tid + 1024] = r[2];
  };
  auto phase_barrier = [&]() {
    asm volatile("s_waitcnt lgkmcnt(0)" ::: "memory");  // my ds_writes visible
    __builtin_amdgcn_s_barrier();                       // vmcnt NOT drained
    __builtin_amdgcn_sched_barrier(0);
  };

  const int cb0 = (trow + 28) * HCOLS + 28 + 2 * tx;    // center px0 halo idx
  const int cb1 = cb0 + 16 * HCOLS;

  f2 ssv[2][NS];
  #pragma unroll
  for (int q = 0; q < 2; ++q)
    #pragma unroll
    for (int s = 0; s < NS; ++s) ssv[q][s] = f2{0.f, 0.f};

  auto compute_emb = [&](int P) {           // channel in buf4[P]
    const float* bufp = (const float*)buf4[P];
    #pragma unroll
    for (int q = 0; q < 2; ++q) {
      const int cb = q ? cb1 : cb0;
      const f2 cc = *reinterpret_cast<const f2*>(bufp + cb);  // 8B aligned
      #pragma unroll
      for (int s = 0; s < NS; ++s) {
        const int a = cb + soff[s];         // stays inside halo
        f2 sh; sh[0] = bufp[a]; sh[1] = bufp[a + 1];
        const f2 d = cc - sh;
        ssv[q][s][0] = fmaf(d[0], d[0], ssv[q][s][0]);
        ssv[q][s][1] = fmaf(d[1], d[1], ssv[q][s][1]);
      }
    }
  };

  // Prologue: ch0 staged (one exposed latency), ch1 in flight.
  stage_load(0);
  stage_write(0);
  stage_load(1);
  phase_barrier();

  // Steady state: compute(e) | write(e+1) | issue load(e+2) | barrier.
  // write(e+1)'s vmcnt wait covers loads issued one full phase earlier.
  #pragma unroll
  for (int m = 0; m < 6; ++m) {
    const int e = 2 * m;
    compute_emb(0);                   // ch e   (even -> buf 0)
    stage_write(1);                   // ch e+1 -> buf 1
    stage_load(e + 2);                // ch e+2 (<=12 always)
    phase_barrier();

    compute_emb(1);                   // ch e+1
    stage_write(0);                   // ch e+2 -> buf 0
    if (e + 3 < NC) stage_load(e + 3);
    phase_barrier();
  }

  // Seg channel (ch 12, buf 0): bit-exact int compare + dice sums.
  float numa[NS], dena[NS];
  {
    const float* bufp = (const float*)buf4[0];
    #pragma unroll
    for (int s = 0; s < NS; ++s) { numa[s] = 0.f; dena[s] = 0.f; }
    #pragma unroll
    for (int q = 0; q < 2; ++q) {
      const int cb = q ? cb1 : cb0;
      const int tc0 = __float_as_int(bufp[cb]);
      const int tc1 = __float_as_int(bufp[cb + 1]);
      #pragma unroll
      for (int s = 0; s < NS; ++s) {
        const int a = cb + soff[s];
        const int t0 = __float_as_int(bufp[a]);
        const int t1 = __float_as_int(bufp[a + 1]);
        {
          const float n  = __builtin_amdgcn_sqrtf(ssv[q][s][0]);
          const float rc = fmaxf(fmaf(n, -(1.0f / 3.0f), 1.0f), 0.0f);
          const float A  = fmaf(-rc, rc, 1.0f);
          const float ta = (tc0 == t0) ? 0.f : 1.f;
          numa[s] = fmaf(A, ta, numa[s]);
          dena[s] += fmaf(A, A, ta);
        }
        {
          const float n  = __builtin_amdgcn_sqrtf(ssv[q][s][1]);
          const float rc = fmaxf(fmaf(n, -(1.0f / 3.0f), 1.0f), 0.0f);
          const float A  = fmaf(-rc, rc, 1.0f);
          const float ta = (tc1 == t1) ? 0.f : 1.f;
          numa[s] = fmaf(A, ta, numa[s]);
          dena[s] += fmaf(A, A, ta);
        }
      }
    }
  }

  // block reduction: [0..7]=num, [8..15]=den
  float arr[16];
  #pragma unroll
  for (int s = 0; s < NS; ++s) { arr[s] = numa[s]; arr[8 + s] = dena[s]; }
  #pragma unroll
  for (int k = 0; k < 16; ++k) {
    float v = arr[k];
    #pragma unroll
    for (int o = 32; o > 0; o >>= 1) v += __shfl_down(v, o, 64);
    arr[k] = v;
  }
  const int lane = tid & 63;
  if (lane == 0) {
    #pragma unroll
    for (int k = 0; k < 16; ++k) red[wv][k] = arr[k];
  }
  __syncthreads();
  if (tid < 16) {
    float v = 0.f;
    #pragma unroll
    for (int w = 0; w < 8; ++w) v += red[w][tid];
    partial[tid * NBLK + blockIdx.x] = v;   // [channel][block]
  }
}

__global__ __launch_bounds__(1024) void affloss_final(
    const float* __restrict__ partial, float* __restrict__ out) {
  __shared__ double csum[16];
  const int lane = threadIdx.x & 63, wv = threadIdx.x >> 6;  // wv = channel

  double s = 0.0;
  for (int i = lane; i < NBLK; i += 64)
    s += (double)partial[wv * NBLK + i];
  #pragma unroll
  for (int o = 32; o > 0; o >>= 1) s += __shfl_down(s, o, 64);
  if (lane == 0) csum[wv] = s;
  __syncthreads();

  if (threadIdx.x == 0) {
    double total = 0.0;
    #pragma unroll
    for (int c = 0; c < 8; ++c) {
      double num = csum[c];
      double den = csum[8 + c];
      if (den < 1e-7) den = 1e-7;            // maximum(den, EPS)
      total += 1.0 - 2.0 * num / den;
    }
    out[0] = (float)total;
  }
}

extern "C" void kernel_launch(void* const* d_in, const int* in_sizes, int n_in,
                              void* d_out, int out_size, void* d_ws, size_t ws_size,
                              hipStream_t stream) {
  const float* emb  = (const float*)d_in[0];
  const int*   seg  = (const int*)d_in[1];
  const int*   offs = (const int*)d_in[2];
  float* partial = (float*)d_ws;   // 16*512 floats = 32,768 B

  affloss_main<<<NBLK, 512, 0, stream>>>(emb, seg, offs, partial);
  affloss_final<<<1, 1024, 0, stream>>>(partial, (float*)d_out);
}

// Round 12
// 59.370 us; speedup vs baseline: 3.9606x; 3.9606x over previous
//
#include <hip/hip_runtime.h>

// AffinitySideLoss: B=4, E=12, H=W=512, S=8 offsets, output = 1 float scalar.
// d_in[0] = input_ float32 [4,12,512,512]
// d_in[1] = target int32   [4,1,512,512]
// d_in[2] = offsets int32  [8,2]  (values in [-27,0))
// d_out   = float32 [1]
// d_ws    = per-block partials: float [16][1024]  (64 KB)
//
// R12: L1-resident supertile, DIRECT loads (no LDS, no barriers, no
// staging). Block = 16x64-px tile; per channel, center + all 8 shifted
// reads fall inside a 44x92 halo = 16.2 KB; 2 blocks/CU -> both halos fit
// the 32 KB L1. e-major loop: first touch of a line misses (L2 fill, 215 MB
// total at the measured ~18.6 B/cyc/CU), remaining ~8x of the 550 MB demand
// hit L1. R4/R7's working set (full 512-col rows, 58+ KB) could never hit
// L1 - that was the ~45us wall. No R9-R11 failure modes possible here.

typedef float f2 __attribute__((ext_vector_type(2)));
typedef float f2u __attribute__((ext_vector_type(2), aligned(4)));
typedef int   i2 __attribute__((ext_vector_type(2)));
typedef int   i2u __attribute__((ext_vector_type(2), aligned(4)));

#define HWSZ  262144     // 512*512
#define NE    12
#define NS    8
#define TROWS 16
#define TCOLS 64
#define NBLK  1024       // 4 batches x 32 row-tiles x 8 col-tiles

__global__ __launch_bounds__(512) void affloss_main(
    const float* __restrict__ emb, const int* __restrict__ seg,
    const int* __restrict__ offs, float* __restrict__ partial) {
  // XCD swizzle (bijective, 1024 % 8 == 0): contiguous tile band per XCD so
  // neighbor-tile halo overlap hits that XCD's L2.
  const int bid = blockIdx.x;
  const int nb  = (bid & 7) * (NBLK / 8) + (bid >> 3);
  const int b   = nb >> 8;              // batch 0..3
  const int rem = nb & 255;             // 32 row-tiles x 8 col-tiles
  const int r0  = (rem >> 3) * TROWS;   // 0..496
  const int c0  = (rem & 7) * TCOLS;    // 0..448

  const int tid = threadIdx.x;
  const int tx  = tid & 31;             // f2 col: cols c0+2tx, c0+2tx+1
  const int row = tid >> 5;             // tile row 0..15

  const float* embB = emb + (size_t)b * NE * HWSZ;
  const int*   segB = seg + (size_t)b * HWSZ;

  const int r = r0 + row;               // center row
  const int cw = c0 + 2 * tx;           // center col (px0)
  const int base = (r << 9) + cw;

  // Per-offset addressing (offsets read at uniform addresses -> scalar).
  int rowo[NS];                         // clamped shifted-row start
  int colv[NS];                         // clamped column (>=0)
  bool brd[NS];                         // left border: both px -> col 0
  #pragma unroll
  for (int s = 0; s < NS; ++s) {
    const int oy = offs[2 * s];
    const int ox = offs[2 * s + 1];
    int hs = r + oy; hs = hs < 0 ? 0 : hs;     // replication clamp (top)
    rowo[s] = hs << 9;
    const int wsb = cw + ox;                   // >= -27 only when c0 == 0
    brd[s]  = wsb < 0;
    colv[s] = wsb < 0 ? 0 : wsb;
  }

  f2 ssv[NS];
  #pragma unroll
  for (int s = 0; s < NS; ++s) ssv[s] = f2{0.f, 0.f};

  // Hot loop: 9 loads per channel, all within the block's 16.2 KB halo.
  #pragma unroll 2
  for (int e = 0; e < NE; ++e) {
    const float* embE = embB + e * HWSZ;
    const f2 ce = *reinterpret_cast<const f2*>(embE + base);
    #pragma unroll
    for (int s = 0; s < NS; ++s) {
      f2 sh = *reinterpret_cast<const f2u*>(embE + rowo[s] + colv[s]);
      sh[1] = brd[s] ? sh[0] : sh[1];          // border: both px = col 0
      const float d0 = ce[0] - sh[0];
      const float d1 = ce[1] - sh[1];
      ssv[s][0] = fmaf(d0, d0, ssv[s][0]);
      ssv[s][1] = fmaf(d1, d1, ssv[s][1]);
    }
  }

  // Epilogue: seg affinities (9 reads, same halo pattern) + dice partials.
  const i2 tc = *reinterpret_cast<const i2u*>(segB + base);
  float arr[16];                        // [0..7]=num, [8..15]=den
  #pragma unroll
  for (int s = 0; s < NS; ++s) {
    i2 ts = *reinterpret_cast<const i2u*>(segB + rowo[s] + colv[s]);
    ts[1] = brd[s] ? ts[0] : ts[1];

    float nacc = 0.f, dacc = 0.f;
    #pragma unroll
    for (int j = 0; j < 2; ++j) {
      const float ss = ssv[s][j];                // >= 0 by construction
      const float n  = __builtin_amdgcn_sqrtf(ss);  // sqrt(0)=0 covers where()
      const float rc = fmaxf(fmaf(n, -(1.0f / 3.0f), 1.0f), 0.0f);
      const float a  = fmaf(-rc, rc, 1.0f);      // affinity = 1 - r^2
      const float ta = (tc[j] == ts[j]) ? 0.f : 1.f;
      nacc = fmaf(a, ta, nacc);
      dacc += fmaf(a, a, ta);                    // a^2 + ta  (ta^2 == ta)
    }
    arr[s] = nacc;
    arr[8 + s] = dacc;
  }

  // wave (64-lane) shuffle reduction per channel -> block partials
  #pragma unroll
  for (int k = 0; k < 16; ++k) {
    float v = arr[k];
    #pragma unroll
    for (int o = 32; o > 0; o >>= 1) v += __shfl_down(v, o, 64);
    arr[k] = v;
  }

  __shared__ float red[8][16];
  const int lane = tid & 63, wv = tid >> 6;
  if (lane == 0) {
    #pragma unroll
    for (int k = 0; k < 16; ++k) red[wv][k] = arr[k];
  }
  __syncthreads();
  if (tid < 16) {
    float v = 0.f;
    #pragma unroll
    for (int w = 0; w < 8; ++w) v += red[w][tid];
    partial[tid * NBLK + blockIdx.x] = v;   // [channel][block]
  }
}

__global__ __launch_bounds__(1024) void affloss_final(
    const float* __restrict__ partial, float* __restrict__ out) {
  __shared__ double csum[16];
  const int lane = threadIdx.x & 63, wv = threadIdx.x >> 6;  // wv = channel

  double s = 0.0;
  for (int i = lane; i < NBLK; i += 64)
    s += (double)partial[wv * NBLK + i];
  #pragma unroll
  for (int o = 32; o > 0; o >>= 1) s += __shfl_down(s, o, 64);
  if (lane == 0) csum[wv] = s;
  __syncthreads();

  if (threadIdx.x == 0) {
    double total = 0.0;
    #pragma unroll
    for (int c = 0; c < 8; ++c) {
      double num = csum[c];
      double den = csum[8 + c];
      if (den < 1e-7) den = 1e-7;            // maximum(den, EPS)
      total += 1.0 - 2.0 * num / den;
    }
    out[0] = (float)total;
  }
}

extern "C" void kernel_launch(void* const* d_in, const int* in_sizes, int n_in,
                              void* d_out, int out_size, void* d_ws, size_t ws_size,
                              hipStream_t stream) {
  const float* emb  = (const float*)d_in[0];
  const int*   seg  = (const int*)d_in[1];
  const int*   offs = (const int*)d_in[2];
  float* partial = (float*)d_ws;   // 16*1024 floats = 65,536 B

  affloss_main<<<NBLK, 512, 0, stream>>>(emb, seg, offs, partial);
  affloss_final<<<1, 1024, 0, stream>>>(partial, (float*)d_out);
}

// Round 13
// 55.732 us; speedup vs baseline: 4.2191x; 1.0653x over previous
//
#include <hip/hip_runtime.h>

// AffinitySideLoss: B=4, E=12, H=W=512, S=8 offsets, output = 1 float scalar.
// d_in[0] = input_ float32 [4,12,512,512]
// d_in[1] = target int32   [4,1,512,512]
// d_in[2] = offsets int32  [8,2]  (values in [-27,0))
// d_out   = float32 [1]
// d_ws    = per-block partials: float [16][1024]  (64 KB)
//
// R13: 16x64 supertile, TRIPLE-buffered LDS halo, prefetch distance 2,
// one raw (lgkmcnt-only) barrier per channel. Straight-line code - no
// lambdas, no sched_barrier, no launch_bounds min-wave (R11's spill came
// from that combination). Loads for channel e+2 issue at the top of iter e
// into reg set A/B (alternating) and are ds_written at iter e+1 -> ~1.5
// phases (>400 cyc) of latency cover, and the vmcnt at the raw barrier is
// NOT drained (that drain was R9/R10's serializer). Border splat applied
// at the WRITE site so no early vmcnt waits. Demand: 1024 blk x 13 ch x
// 16.2 KB = 215 MB vs 490 MB direct (R4) - and R4's ~29cyc/VMEM-instr cap
// scales with instruction count, which drops 117 -> 52 per thread.

typedef float f2 __attribute__((ext_vector_type(2)));

#define HWSZ  262144     // 512*512
#define NE    12
#define NC    13         // 12 emb + seg (bit container)
#define NS    8
#define TROWS 16
#define TCOLS 64
#define NBLK  1024       // 4 batches x 32 row-tiles x 8 col-tiles
#define HROWS 44         // rows r0-28 .. r0+15
#define HCOLS 92         // cols c0-28 .. c0+63
#define HF2   2024       // HROWS*HCOLS/2 f2 slots

__global__ __launch_bounds__(512) void affloss_main(
    const float* __restrict__ emb, const int* __restrict__ seg,
    const int* __restrict__ offs, float* __restrict__ partial) {
  __shared__ f2 lbuf[3][HF2];           // 3 x 16,192 B = 48,576 B
  __shared__ float red[8][16];

  // XCD swizzle (bijective, 1024 % 8 == 0)
  const int bid = blockIdx.x;
  const int nb  = (bid & 7) * (NBLK / 8) + (bid >> 3);
  const int b   = nb >> 8;
  const int rem = nb & 255;
  const int r0  = (rem >> 3) * TROWS;   // 0..496
  const int c0  = (rem & 7) * TCOLS;    // 0..448

  const int tid = threadIdx.x;
  const int tx  = tid & 31;             // px cols c0+2tx, c0+2tx+1
  const int row = tid >> 5;             // tile row 0..15

  const float* embB = emb + (size_t)b * NE * HWSZ;
  const float* segF = (const float*)(seg + (size_t)b * HWSZ);  // bit container

  int soff[NS];                         // halo-space offsets (SGPR)
  #pragma unroll
  for (int s = 0; s < NS; ++s)
    soff[s] = offs[2 * s] * HCOLS + offs[2 * s + 1];

  // Staging geometry: f2 slot = tid + k*512 (k=3 only for tid<488).
  // slot -> (halo row rr, col 2*(slot%46)); row clamps at 0; fully-left
  // columns (gc < 0, always even -> both px negative) splat col 0.
  int sadd0, sadd1, sadd2, sadd3;
  bool sp0, sp1, sp2, sp3;
  {
    int slot, rr, gc, gr;
    slot = tid;            rr = slot / 46; gc = c0 - 28 + 2 * (slot - rr * 46);
    gr = r0 - 28 + rr; gr = gr < 0 ? 0 : gr;
    sp0 = gc < 0; sadd0 = (gr << 9) + (gc < 0 ? 0 : gc);
    slot = tid + 512;      rr = slot / 46; gc = c0 - 28 + 2 * (slot - rr * 46);
    gr = r0 - 28 + rr; gr = gr < 0 ? 0 : gr;
    sp1 = gc < 0; sadd1 = (gr << 9) + (gc < 0 ? 0 : gc);
    slot = tid + 1024;     rr = slot / 46; gc = c0 - 28 + 2 * (slot - rr * 46);
    gr = r0 - 28 + rr; gr = gr < 0 ? 0 : gr;
    sp2 = gc < 0; sadd2 = (gr << 9) + (gc < 0 ? 0 : gc);
    slot = tid + 1536;     rr = slot / 46; gc = c0 - 28 + 2 * (slot - rr * 46);
    gr = r0 - 28 + rr; gr = gr < 0 ? 0 : gr;
    sp3 = gc < 0; sadd3 = (gr << 9) + (gc < 0 ? 0 : gc);
  }
  const bool has3 = tid < (HF2 - 1536);   // 488 threads own slot 3

// issue 4 coalesced f2 loads for plane P into regs R0..R3 (no data use here)
#define LOADSET(R0, R1, R2, R3, P) do {                                   \
    const float* _pl = (P);                                               \
    R0 = *reinterpret_cast<const f2*>(_pl + sadd0);                       \
    R1 = *reinterpret_cast<const f2*>(_pl + sadd1);                       \
    R2 = *reinterpret_cast<const f2*>(_pl + sadd2);                       \
    if (has3) R3 = *reinterpret_cast<const f2*>(_pl + sadd3);             \
  } while (0)

// splat-fix (edge lanes) + ds_write into buffer bi; vmcnt waits land here
#define WRITESET(bi, R0, R1, R2, R3) do {                                 \
    if (sp0) R0[1] = R0[0];                                               \
    if (sp1) R1[1] = R1[0];                                               \
    if (sp2) R2[1] = R2[0];                                               \
    lbuf[bi][tid]        = R0;                                            \
    lbuf[bi][tid + 512]  = R1;                                            \
    lbuf[bi][tid + 1024] = R2;                                            \
    if (has3) { if (sp3) R3[1] = R3[0]; lbuf[bi][tid + 1536] = R3; }      \
  } while (0)

// raw barrier: drain LDS writes only; vmcnt prefetch stays in flight
#define PHASEBAR() do {                                                   \
    asm volatile("s_waitcnt lgkmcnt(0)" ::: "memory");                    \
    __builtin_amdgcn_s_barrier();                                         \
  } while (0)

  const int cb = (row + 28) * HCOLS + 28 + 2 * tx;   // center px0 halo idx

  f2 ssv[NS];
  #pragma unroll
  for (int s = 0; s < NS; ++s) ssv[s] = f2{0.f, 0.f};

// emb compute for channel in buffer bi
#define COMPUTE(bi) do {                                                  \
    const float* _bp = (const float*)lbuf[bi];                            \
    const float c00 = _bp[cb], c01 = _bp[cb + 1];                         \
    _Pragma("unroll")                                                     \
    for (int s = 0; s < NS; ++s) {                                        \
      const int _a = cb + soff[s];                                        \
      const float s0 = _bp[_a], s1 = _bp[_a + 1];                         \
      const float d0 = c00 - s0, d1 = c01 - s1;                           \
      ssv[s][0] = fmaf(d0, d0, ssv[s][0]);                                \
      ssv[s][1] = fmaf(d1, d1, ssv[s][1]);                                \
    }                                                                     \
  } while (0)

  f2 A0, A1, A2, A3, B0, B1, B2, B3;

  // prologue: ch0 + ch1 in flight; ch0 written (one exposed latency)
  LOADSET(A0, A1, A2, A3, embB);
  LOADSET(B0, B1, B2, B3, embB + HWSZ);
  WRITESET(0, A0, A1, A2, A3);
  PHASEBAR();

  // steady state: issue load(e+2) | compute(e) | write(e+1) | barrier
  LOADSET(A0, A1, A2, A3, embB + 2 * HWSZ);   // e=0
  COMPUTE(0); WRITESET(1, B0, B1, B2, B3); PHASEBAR();
  LOADSET(B0, B1, B2, B3, embB + 3 * HWSZ);   // e=1
  COMPUTE(1); WRITESET(2, A0, A1, A2, A3); PHASEBAR();
  LOADSET(A0, A1, A2, A3, embB + 4 * HWSZ);   // e=2
  COMPUTE(2); WRITESET(0, B0, B1, B2, B3); PHASEBAR();
  LOADSET(B0, B1, B2, B3, embB + 5 * HWSZ);   // e=3
  COMPUTE(0); WRITESET(1, A0, A1, A2, A3); PHASEBAR();
  LOADSET(A0, A1, A2, A3, embB + 6 * HWSZ);   // e=4
  COMPUTE(1); WRITESET(2, B0, B1, B2, B3); PHASEBAR();
  LOADSET(B0, B1, B2, B3, embB + 7 * HWSZ);   // e=5
  COMPUTE(2); WRITESET(0, A0, A1, A2, A3); PHASEBAR();
  LOADSET(A0, A1, A2, A3, embB + 8 * HWSZ);   // e=6
  COMPUTE(0); WRITESET(1, B0, B1, B2, B3); PHASEBAR();
  LOADSET(B0, B1, B2, B3, embB + 9 * HWSZ);   // e=7
  COMPUTE(1); WRITESET(2, A0, A1, A2, A3); PHASEBAR();
  LOADSET(A0, A1, A2, A3, embB + 10 * HWSZ);  // e=8
  COMPUTE(2); WRITESET(0, B0, B1, B2, B3); PHASEBAR();
  LOADSET(B0, B1, B2, B3, embB + 11 * HWSZ);  // e=9
  COMPUTE(0); WRITESET(1, A0, A1, A2, A3); PHASEBAR();
  LOADSET(A0, A1, A2, A3, segF);              // e=10 (seg bits)
  COMPUTE(1); WRITESET(2, B0, B1, B2, B3); PHASEBAR();
  /* e=11: no more loads */
  COMPUTE(2); WRITESET(0, A0, A1, A2, A3); PHASEBAR();

  // e=12: seg channel in buffer 0 - bit-exact compare + dice sums
  float numa[NS], dena[NS];
  {
    const float* bp = (const float*)lbuf[0];
    const int tc0 = __float_as_int(bp[cb]);
    const int tc1 = __float_as_int(bp[cb + 1]);
    #pragma unroll
    for (int s = 0; s < NS; ++s) {
      const int a = cb + soff[s];
      const int t0 = __float_as_int(bp[a]);
      const int t1 = __float_as_int(bp[a + 1]);
      float nacc = 0.f, dacc = 0.f;
      {
        const float n  = __builtin_amdgcn_sqrtf(ssv[s][0]);
        const float rc = fmaxf(fmaf(n, -(1.0f / 3.0f), 1.0f), 0.0f);
        const float A  = fmaf(-rc, rc, 1.0f);
        const float ta = (tc0 == t0) ? 0.f : 1.f;
        nacc = fmaf(A, ta, nacc); dacc += fmaf(A, A, ta);
      }
      {
        const float n  = __builtin_amdgcn_sqrtf(ssv[s][1]);
        const float rc = fmaxf(fmaf(n, -(1.0f / 3.0f), 1.0f), 0.0f);
        const float A  = fmaf(-rc, rc, 1.0f);
        const float ta = (tc1 == t1) ? 0.f : 1.f;
        nacc = fmaf(A, ta, nacc); dacc += fmaf(A, A, ta);
      }
      numa[s] = nacc; dena[s] = dacc;
    }
  }

  // block reduction: [0..7]=num, [8..15]=den
  float arr[16];
  #pragma unroll
  for (int s = 0; s < NS; ++s) { arr[s] = numa[s]; arr[8 + s] = dena[s]; }
  #pragma unroll
  for (int k = 0; k < 16; ++k) {
    float v = arr[k];
    #pragma unroll
    for (int o = 32; o > 0; o >>= 1) v += __shfl_down(v, o, 64);
    arr[k] = v;
  }
  const int lane = tid & 63, wv = tid >> 6;
  if (lane == 0) {
    #pragma unroll
    for (int k = 0; k < 16; ++k) red[wv][k] = arr[k];
  }
  __syncthreads();
  if (tid < 16) {
    float v = 0.f;
    #pragma unroll
    for (int w = 0; w < 8; ++w) v += red[w][tid];
    partial[tid * NBLK + blockIdx.x] = v;   // [channel][block]
  }
}

__global__ __launch_bounds__(1024) void affloss_final(
    const float* __restrict__ partial, float* __restrict__ out) {
  __shared__ double csum[16];
  const int lane = threadIdx.x & 63, wv = threadIdx.x >> 6;  // wv = channel

  double s = 0.0;
  for (int i = lane; i < NBLK; i += 64)
    s += (double)partial[wv * NBLK + i];
  #pragma unroll
  for (int o = 32; o > 0; o >>= 1) s += __shfl_down(s, o, 64);
  if (lane == 0) csum[wv] = s;
  __syncthreads();

  if (threadIdx.x == 0) {
    double total = 0.0;
    #pragma unroll
    for (int c = 0; c < 8; ++c) {
      double num = csum[c];
      double den = csum[8 + c];
      if (den < 1e-7) den = 1e-7;            // maximum(den, EPS)
      total += 1.0 - 2.0 * num / den;
    }
    out[0] = (float)total;
  }
}

extern "C" void kernel_launch(void* const* d_in, const int* in_sizes, int n_in,
                              void* d_out, int out_size, void* d_ws, size_t ws_size,
                              hipStream_t stream) {
  const float* emb  = (const float*)d_in[0];
  const int*   seg  = (const int*)d_in[1];
  const int*   offs = (const int*)d_in[2];
  float* partial = (float*)d_ws;   // 16*1024 floats = 65,536 B

  affloss_main<<<NBLK, 512, 0, stream>>>(emb, seg, offs, partial);
  affloss_final<<<1, 1024, 0, stream>>>(partial, (float*)d_out);
}